// Round 8
// baseline (3733.366 us; speedup 1.0000x reference)
//
#include <hip/hip_runtime.h>

typedef __attribute__((ext_vector_type(8))) short short8v;
typedef __attribute__((ext_vector_type(4))) float f32x4;
typedef __attribute__((ext_vector_type(4))) float float4v;
typedef unsigned long long u64;

#define NHID 1024
#define NCAT 1024
#define NB   64
#define NT   512
#define RING_STRIDE 65536   // shorts per ring slot (128 KB)

__device__ __forceinline__ short f2bf(float f) {
  union { float f; unsigned u; } c; c.f = f;
  unsigned r = (c.u + 0x7fffu + ((c.u >> 16) & 1u)) >> 16;
  return (short)r;
}

__device__ __forceinline__ short8v cvt8(float4v a, float4v b) {
  short8v s;
  s[0]=f2bf(a[0]); s[1]=f2bf(a[1]); s[2]=f2bf(a[2]); s[3]=f2bf(a[3]);
  s[4]=f2bf(b[0]); s[5]=f2bf(b[1]); s[6]=f2bf(b[2]); s[7]=f2bf(b[3]);
  return s;
}

// 256 persistent wgs x 256 threads; wg=(mt,cg) owns h-tile rows mt*16.. x cols cg*16..
// Symmetric 4-way K-split: wave wv handles h-K [wv*256,+256) AND x-K [wv*256,+256)
// (x prefetched one step ahead, fp32->bf16 in-register). Each wave polls only its
// 16 producers (cg in [wv*16,+16)), hot-spin, then cached h loads (per-XCD L2
// serves the 64x broadcast; ring addresses are write-once so staleness is
// impossible after flag confirmation). Distributed epilogue: partials in LDS
// lane-major (conflict-free b128 writes), each of 256 threads reduces+activates
// ONE (row,col) element (h state thread-resident fp32) and publishes its own
// u16 agent-atomic store. vmcnt drain + barrier + tid0 flag. No per-step fence.
__global__ __launch_bounds__(256, 1) void gru_kernel(
    const float* __restrict__ h0, const float* __restrict__ Wh, const float* __restrict__ Wz,
    const float* __restrict__ Uh, const float* __restrict__ Uz, const float* __restrict__ bz,
    const float* __restrict__ Wout, const float* __restrict__ x,
    short* __restrict__ ring, unsigned* __restrict__ flags, float* __restrict__ out)
{
  extern __shared__ char smem[];
  short8v* ufr = (short8v*)smem;            // weight B-frags, 128 KB
  float*   red = (float*)(smem + 131072);   // partials [slot=wv*2+g][lane][4] f32, 8 KB

  __builtin_amdgcn_fence(__ATOMIC_ACQUIRE, "agent");  // once: kill cross-launch stale lines

  const int tid  = threadIdx.x;
  const int lane = tid & 63;
  const int wv   = tid >> 6;
  const int mt   = blockIdx.x >> 6;
  const int cg   = blockIdx.x & 63;
  const int col  = lane & 15;
  const int quad = lane >> 4;
  const int kq   = quad * 8;
  const int row_t = tid >> 4;       // epilogue element (row_t, col_t)
  const int col_t = tid & 15;
  const int jg_t  = cg * 16 + col_t;

  // ---- one-time: weight B-fragments into LDS (16 cols x K=2048 x 2 gates) ----
  for (int idx = tid; idx < 64 * 2 * 64; idx += 256) {
    int l  = idx & 63;
    int nt = (idx >> 6) & 1;
    int kb = idx >> 7;
    int j  = cg * 16 + (l & 15);
    int k0 = (kb & 31) * 32 + (l >> 4) * 8;
    const float* M = (kb < 32) ? (nt ? Uh : Uz) : (nt ? Wh : Wz);
    short8v v;
#pragma unroll
    for (int e = 0; e < 8; ++e) v[e] = f2bf(M[j * 1024 + k0 + e]);
    ufr[idx] = v;
  }
  __syncthreads();

  float hl  = h0[(mt * 16 + row_t) * NHID + jg_t];   // thread-resident fp32 h state
  const float bzv = bz[jg_t];

  const int kb0h = wv * 8;          // h k-range (kb units of 32)
  const int kb0x = 32 + wv * 8;     // x k-range
  unsigned* myflag = flags + (mt * 64 + cg) * 16;
  const unsigned* pollp = flags + (mt * 64 + wv * 16 + (lane & 15)) * 16;

  short8v xf[8];
  {  // preload x_0
    const float* xrow = x + ((long)(mt * 16 + col) * NT + 0) * NCAT + (kb0x - 32) * 32 + kq;
#pragma unroll
    for (int i = 0; i < 8; ++i)
      xf[i] = cvt8(*(const float4v*)(xrow + i * 32), *(const float4v*)(xrow + i * 32 + 4));
  }

  for (int t = 0; t < NT; ++t) {
    short8v hf[8];
    if (t > 0) {
      const unsigned tt = (unsigned)t;
      for (;;) {   // hot spin: 1 flag load in flight, 16 lines
        unsigned v = __hip_atomic_load(pollp, __ATOMIC_RELAXED, __HIP_MEMORY_SCOPE_AGENT);
        if (__ballot(v < tt) == 0ull) break;
      }
      __asm__ volatile("" ::: "memory");   // keep cached h loads below poll exit
      const short* hrow = ring + (size_t)t * RING_STRIDE
                        + (mt * 16 + col) * 1024 + kb0h * 32 + kq;
#pragma unroll
      for (int i = 0; i < 8; ++i) hf[i] = *(const short8v*)(hrow + i * 32);
    } else {
      const float* hrow = h0 + (mt * 16 + col) * NHID + kb0h * 32 + kq;
#pragma unroll
      for (int i = 0; i < 8; ++i)
        hf[i] = cvt8(*(const float4v*)(hrow + i * 32), *(const float4v*)(hrow + i * 32 + 4));
    }

    f32x4 pz = {0.f,0.f,0.f,0.f}, ph = {0.f,0.f,0.f,0.f};
#pragma unroll
    for (int i = 0; i < 8; ++i) {
      int kb = kb0h + i;
      pz = __builtin_amdgcn_mfma_f32_16x16x32_bf16(hf[i], ufr[kb * 128 + lane],      pz, 0, 0, 0);
      ph = __builtin_amdgcn_mfma_f32_16x16x32_bf16(hf[i], ufr[kb * 128 + 64 + lane], ph, 0, 0, 0);
    }
#pragma unroll
    for (int i = 0; i < 8; ++i) {
      int kb = kb0x + i;
      pz = __builtin_amdgcn_mfma_f32_16x16x32_bf16(xf[i], ufr[kb * 128 + lane],      pz, 0, 0, 0);
      ph = __builtin_amdgcn_mfma_f32_16x16x32_bf16(xf[i], ufr[kb * 128 + 64 + lane], ph, 0, 0, 0);
    }

    // partials -> LDS, lane-major (conflict-free b128)
    ((f32x4*)red)[(wv * 2 + 0) * 64 + lane] = pz;
    ((f32x4*)red)[(wv * 2 + 1) * 64 + lane] = ph;
    __syncthreads();   // barrier A: partials ready

    // distributed reduce + epilogue: thread -> element (row_t, col_t)
    {
      const int idx = 4 * ((row_t >> 2) * 16 + col_t) + (row_t & 3);
      float accz = red[idx] + red[512 + idx] + red[1024 + idx] + red[1536 + idx];
      float acch = red[256 + idx] + red[768 + idx] + red[1280 + idx] + red[1792 + idx];
      float zp = accz + bzv;
      float z  = 1.f / (1.f + __expf(-zp));
      float ht = 2.f / (1.f + __expf(-2.f * acch)) - 1.f;
      float v  = hl + z * (ht - hl);
      hl = v;
      unsigned short* dst = (unsigned short*)(ring + (size_t)(t + 1) * RING_STRIDE
                                              + (mt * 16 + row_t) * 1024 + jg_t);
      __hip_atomic_store(dst, (unsigned short)f2bf(v),
                         __ATOMIC_RELAXED, __HIP_MEMORY_SCOPE_AGENT);
    }
    __asm__ volatile("s_waitcnt vmcnt(0)" ::: "memory");   // own stores at coherence point
    __syncthreads();   // barrier B: whole tile drained (+ red safe for next write)
    if (tid == 0)
      __hip_atomic_store(myflag, (unsigned)(t + 1), __ATOMIC_RELAXED, __HIP_MEMORY_SCOPE_AGENT);

    if (t + 1 < NT) {  // x prefetch flies during next poll (L2-hot after pass 1)
      const float* xrow = x + ((long)(mt * 16 + col) * NT + (t + 1)) * NCAT + (kb0x - 32) * 32 + kq;
#pragma unroll
      for (int i = 0; i < 8; ++i)
        xf[i] = cvt8(*(const float4v*)(xrow + i * 32), *(const float4v*)(xrow + i * 32 + 4));
    }
  }

  // ---- tail: out = hT @ Wout.T (hT = ring[NT]). K-split 256/wave ----
  {
    for (;;) {
      unsigned v = __hip_atomic_load(pollp, __ATOMIC_RELAXED, __HIP_MEMORY_SCOPE_AGENT);
      if (__ballot(v < (unsigned)NT) == 0ull) break;
    }
    __asm__ volatile("" ::: "memory");
    const int jg = cg * 16 + col;
    const short* hrow = ring + (size_t)NT * RING_STRIDE
                      + (mt * 16 + col) * 1024 + kb0h * 32 + kq;
    f32x4 acc = {0.f,0.f,0.f,0.f};
    const float* wrow = Wout + (long)jg * NHID + kb0h * 32 + kq;
#pragma unroll
    for (int kb = 0; kb < 8; ++kb) {
      short8v a = *(const short8v*)(hrow + kb * 32);
      float4v w0 = *(const float4v*)(wrow + kb * 32);
      float4v w1 = *(const float4v*)(wrow + kb * 32 + 4);
      acc = __builtin_amdgcn_mfma_f32_16x16x32_bf16(a, cvt8(w0, w1), acc, 0, 0, 0);
    }
    if (wv != 0)
      ((f32x4*)red)[(wv - 1) * 64 + lane] = acc;
    __syncthreads();
    if (wv == 0) {
#pragma unroll
      for (int s = 0; s < 3; ++s)
        acc += ((const f32x4*)red)[s * 64 + lane];
#pragma unroll
      for (int r = 0; r < 4; ++r)
        out[(mt * 16 + quad * 4 + r) * NCAT + jg] = acc[r];
    }
  }
}

extern "C" void kernel_launch(void* const* d_in, const int* in_sizes, int n_in,
                              void* d_out, int out_size, void* d_ws, size_t ws_size,
                              hipStream_t stream) {
  const float* x    = (const float*)d_in[0];
  const float* h0   = (const float*)d_in[1];
  const float* Wh   = (const float*)d_in[2];
  const float* Wz   = (const float*)d_in[3];
  const float* Uh   = (const float*)d_in[5];
  const float* Uz   = (const float*)d_in[6];
  const float* bz   = (const float*)d_in[8];
  const float* Wout = (const float*)d_in[10];

  char* ws = (char*)d_ws;
  // layout: flags [0,16K) (256 wgs x 64B) | h-ring 513 x 128K = 64.1 MB
  unsigned* flags = (unsigned*)ws;
  short* ring = (short*)(ws + 16384);

  hipMemsetAsync(flags, 0, 16384, stream);

  hipFuncSetAttribute((const void*)gru_kernel,
                      hipFuncAttributeMaxDynamicSharedMemorySize, 139264);
  gru_kernel<<<256, 256, 139264, stream>>>(h0, Wh, Wz, Uh, Uz, bz, Wout, x,
                                           ring, flags, (float*)d_out);
}

// Round 9
// 2499.172 us; speedup vs baseline: 1.4938x; 1.4938x over previous
//
#include <hip/hip_runtime.h>

typedef __attribute__((ext_vector_type(8))) short short8v;
typedef __attribute__((ext_vector_type(4))) float f32x4;
typedef __attribute__((ext_vector_type(4))) float float4v;
typedef unsigned long long u64;

#define NHID 1024
#define NCAT 1024
#define NB   64
#define NT   512
#define RING_STRIDE 65536   // shorts per ring slot (128 KB)

__device__ __forceinline__ short f2bf(float f) {
  union { float f; unsigned u; } c; c.f = f;
  unsigned r = (c.u + 0x7fffu + ((c.u >> 16) & 1u)) >> 16;
  return (short)r;
}

__device__ __forceinline__ short8v cvt8(float4v a, float4v b) {
  short8v s;
  s[0]=f2bf(a[0]); s[1]=f2bf(a[1]); s[2]=f2bf(a[2]); s[3]=f2bf(a[3]);
  s[4]=f2bf(b[0]); s[5]=f2bf(b[1]); s[6]=f2bf(b[2]); s[7]=f2bf(b[3]);
  return s;
}

// 256 persistent wgs x 256 threads; wg=(mt,cg) owns h-tile rows mt*16.. x cols cg*16..
// R7 overlap structure: waves 0,1 = h-half of K (512 each; poll -> cached ring
// loads -> MFMA); waves 2,3 = x-half (free-running: never poll, prefetch x one
// step ahead). NEW: the serial epilogue runs on waves 2,3 (idle at the barrier,
// no outstanding VMEM -> vmcnt(0) drains only the ring store): ep-wave w
// handles rows w*8..+8 (2 elems/lane, 4 serial expf), publishes 32 coalesced
// u64 bypass stores, drains, stores its own flag cell. Two flag cells per wg
// in one 64B line. Consumers poll 32 producers x 2 cells with 64 lanes.
// h-broadcast served by per-XCD L2 (ring addresses are write-once per launch);
// single acquire fence at kernel entry only.
__global__ __launch_bounds__(256, 1) void gru_kernel(
    const float* __restrict__ h0, const float* __restrict__ Wh, const float* __restrict__ Wz,
    const float* __restrict__ Uh, const float* __restrict__ Uz, const float* __restrict__ bz,
    const float* __restrict__ Wout, const float* __restrict__ x,
    short* __restrict__ ring, unsigned* __restrict__ flags, float* __restrict__ out)
{
  extern __shared__ char smem[];
  short8v* ufr = (short8v*)smem;            // weight B-frags, 128 KB
  float*   red = (float*)(smem + 131072);   // partials [par][slot=wv*2+g][lane][4], 16 KB
  short*   rp  = (short*)(smem + 131072 + 16384);  // repack, 2 x 256 B

  __builtin_amdgcn_fence(__ATOMIC_ACQUIRE, "agent");  // once: kill cross-launch stale lines

  const int tid  = threadIdx.x;
  const int lane = tid & 63;
  const int wv   = tid >> 6;
  const int mt   = blockIdx.x >> 6;
  const int cg   = blockIdx.x & 63;
  const int col  = lane & 15;
  const int quad = lane >> 4;
  const int kq   = quad * 8;

  // ---- one-time: weight B-fragments into LDS (16 cols x K=2048 x 2 gates) ----
  for (int idx = tid; idx < 64 * 2 * 64; idx += 256) {
    int l  = idx & 63;
    int nt = (idx >> 6) & 1;
    int kb = idx >> 7;
    int j  = cg * 16 + (l & 15);
    int k0 = (kb & 31) * 32 + (l >> 4) * 8;
    const float* M = (kb < 32) ? (nt ? Uh : Uz) : (nt ? Wh : Wz);
    short8v v;
#pragma unroll
    for (int e = 0; e < 8; ++e) v[e] = f2bf(M[j * 1024 + k0 + e]);
    ufr[idx] = v;
  }
  __syncthreads();

  // ep state on waves 2,3: ep-wave w = wv-2 handles rows w*8..+8, 2 elems/lane
  const int w    = wv - 2;                  // valid when wv >= 2
  const int r0   = (wv >= 2) ? (w * 8 + (lane >> 4) * 2) : 0;
  const int jg_e = cg * 16 + col;
  float hl[2] = {0.f, 0.f};
  float bzv = 0.f;
  if (wv >= 2) {
    bzv = bz[jg_e];
    hl[0] = h0[(mt * 16 + r0)     * NHID + jg_e];
    hl[1] = h0[(mt * 16 + r0 + 1) * NHID + jg_e];
  }

  const int kb0 = wv * 16;   // wave k-range (kb = 32-K units): wv0,1 = h; wv2,3 = x
  unsigned* flagline = flags + (mt * 64 + cg) * 16;   // cells 0,1 = row-halves
  // consumer poll: 32 producers (cg' = wv*32 + lane>>1) x 2 cells
  const unsigned* pollp  = flags + (mt * 64 + (wv & 1) * 32 + (lane >> 1)) * 16 + (lane & 1);
  // tail poll: producers cg' = wv*16 + ((lane>>1)&15) x 2 cells
  const unsigned* pollpt = flags + (mt * 64 + wv * 16 + ((lane >> 1) & 15)) * 16 + (lane & 1);

  short8v xf[16];
  if (wv >= 2) {             // preload x_0 (fp32 direct, convert in-register)
    const float* xrow = x + ((long)(mt * 16 + col) * NT + 0) * NCAT + (kb0 - 32) * 32 + kq;
#pragma unroll
    for (int i = 0; i < 16; ++i)
      xf[i] = cvt8(*(const float4v*)(xrow + i * 32), *(const float4v*)(xrow + i * 32 + 4));
  }

  for (int t = 0; t < NT; ++t) {
    const int par = t & 1;
    float* redp = red + par * 2048;
    f32x4 pz0 = {0.f,0.f,0.f,0.f}, pz1 = {0.f,0.f,0.f,0.f};
    f32x4 ph0 = {0.f,0.f,0.f,0.f}, ph1 = {0.f,0.f,0.f,0.f};

    if (wv < 2) {
      short8v f[16];
      if (t > 0) {
        const unsigned tt = (unsigned)t;
        for (;;) {
          unsigned v = __hip_atomic_load(pollp, __ATOMIC_RELAXED, __HIP_MEMORY_SCOPE_AGENT);
          if (__ballot(v < tt) == 0ull) break;
          __builtin_amdgcn_s_sleep(1);
        }
        __asm__ volatile("" ::: "memory");   // keep cached h loads below poll exit
        const short* hrow = ring + (size_t)t * RING_STRIDE
                          + (mt * 16 + col) * 1024 + kb0 * 32 + kq;
#pragma unroll
        for (int i = 0; i < 16; ++i) f[i] = *(const short8v*)(hrow + i * 32);  // cached
      } else {
        const float* hrow = h0 + (mt * 16 + col) * NHID + kb0 * 32 + kq;
#pragma unroll
        for (int i = 0; i < 16; ++i)
          f[i] = cvt8(*(const float4v*)(hrow + i * 32), *(const float4v*)(hrow + i * 32 + 4));
      }
#pragma unroll
      for (int i = 0; i < 16; i += 2) {
        int kb = kb0 + i;
        pz0 = __builtin_amdgcn_mfma_f32_16x16x32_bf16(f[i],   ufr[kb * 128 + lane],        pz0, 0, 0, 0);
        ph0 = __builtin_amdgcn_mfma_f32_16x16x32_bf16(f[i],   ufr[kb * 128 + 64 + lane],   ph0, 0, 0, 0);
        pz1 = __builtin_amdgcn_mfma_f32_16x16x32_bf16(f[i+1], ufr[(kb+1) * 128 + lane],    pz1, 0, 0, 0);
        ph1 = __builtin_amdgcn_mfma_f32_16x16x32_bf16(f[i+1], ufr[(kb+1) * 128 + 64 + lane], ph1, 0, 0, 0);
      }
    } else {
#pragma unroll
      for (int i = 0; i < 16; i += 2) {
        int kb = kb0 + i;
        pz0 = __builtin_amdgcn_mfma_f32_16x16x32_bf16(xf[i],   ufr[kb * 128 + lane],        pz0, 0, 0, 0);
        ph0 = __builtin_amdgcn_mfma_f32_16x16x32_bf16(xf[i],   ufr[kb * 128 + 64 + lane],   ph0, 0, 0, 0);
        pz1 = __builtin_amdgcn_mfma_f32_16x16x32_bf16(xf[i+1], ufr[(kb+1) * 128 + lane],    pz1, 0, 0, 0);
        ph1 = __builtin_amdgcn_mfma_f32_16x16x32_bf16(xf[i+1], ufr[(kb+1) * 128 + 64 + lane], ph1, 0, 0, 0);
      }
    }

    // partials -> LDS red[par], slots wv*2 (z) and wv*2+1 (h)
    ((f32x4*)redp)[(wv * 2 + 0) * 64 + lane] = pz0 + pz1;
    ((f32x4*)redp)[(wv * 2 + 1) * 64 + lane] = ph0 + ph1;
    __syncthreads();

    if (wv >= 2) {
      // ---- distributed epilogue on ep-wave w: rows r0, r0+1, col jg_e ----
      float vv[2];
#pragma unroll
      for (int r = 0; r < 2; ++r) {
        int row = r0 + r;
        int ls  = ((row >> 2) << 4) | col;       // source lane in C-layout
        int reg = row & 3;
        float accz = redp[(0*2+0)*256 + ls*4 + reg] + redp[(1*2+0)*256 + ls*4 + reg]
                   + redp[(2*2+0)*256 + ls*4 + reg] + redp[(3*2+0)*256 + ls*4 + reg];
        float acch = redp[(0*2+1)*256 + ls*4 + reg] + redp[(1*2+1)*256 + ls*4 + reg]
                   + redp[(2*2+1)*256 + ls*4 + reg] + redp[(3*2+1)*256 + ls*4 + reg];
        float zp = accz + bzv;
        float z  = 1.f / (1.f + __expf(-zp));
        float ht = 2.f / (1.f + __expf(-2.f * acch)) - 1.f;
        float v  = hl[r] + z * (ht - hl[r]);
        hl[r] = v; vv[r] = v;
      }
      rp[w * 128 + (r0 & 7) * 16 + col]       = f2bf(vv[0]);
      rp[w * 128 + ((r0 + 1) & 7) * 16 + col] = f2bf(vv[1]);
      __asm__ volatile("s_waitcnt lgkmcnt(0)" ::: "memory");   // wave-internal LDS RAW
      if (lane < 32) {  // publish 8 rows x 16 cols as 32 coalesced u64 bypass stores
        u64 val = ((const u64*)(rp + w * 128))[lane];
        int row = w * 8 + (lane >> 2);
        u64* dst = (u64*)(ring + (size_t)(t + 1) * RING_STRIDE
                          + (mt * 16 + row) * 1024 + cg * 16) + (lane & 3);
        __hip_atomic_store(dst, val, __ATOMIC_RELAXED, __HIP_MEMORY_SCOPE_AGENT);
      }
      __asm__ volatile("s_waitcnt vmcnt(0)" ::: "memory");     // only the ring store
      if (lane == 0)
        __hip_atomic_store(flagline + w, (unsigned)(t + 1),
                           __ATOMIC_RELAXED, __HIP_MEMORY_SCOPE_AGENT);
      if (t + 1 < NT) {  // x prefetch AFTER flag: latency hides under consumers' legs
        const float* xrow = x + ((long)(mt * 16 + col) * NT + (t + 1)) * NCAT + (kb0 - 32) * 32 + kq;
#pragma unroll
        for (int i = 0; i < 16; ++i)
          xf[i] = cvt8(*(const float4v*)(xrow + i * 32), *(const float4v*)(xrow + i * 32 + 4));
      }
    }
  }

  // ---- tail: out = hT @ Wout.T (hT = ring[NT], flags NT). K-split 256/wave ----
  {
    for (;;) {
      unsigned v = __hip_atomic_load(pollpt, __ATOMIC_RELAXED, __HIP_MEMORY_SCOPE_AGENT);
      if (__ballot(v < (unsigned)NT) == 0ull) break;
      __builtin_amdgcn_s_sleep(1);
    }
    __asm__ volatile("" ::: "memory");
    const int jg = cg * 16 + col;
    const int kb0t = wv * 8;
    const short* hrow = ring + (size_t)NT * RING_STRIDE
                      + (mt * 16 + col) * 1024 + kb0t * 32 + kq;
    f32x4 acc = {0.f,0.f,0.f,0.f};
    const float* wrow = Wout + (long)jg * NHID + kb0t * 32 + kq;
#pragma unroll
    for (int kb = 0; kb < 8; ++kb) {
      short8v a = *(const short8v*)(hrow + kb * 32);
      float4v w0 = *(const float4v*)(wrow + kb * 32);
      float4v w1 = *(const float4v*)(wrow + kb * 32 + 4);
      acc = __builtin_amdgcn_mfma_f32_16x16x32_bf16(a, cvt8(w0, w1), acc, 0, 0, 0);
    }
    if (wv != 0)
      ((f32x4*)red)[(wv - 1) * 64 + lane] = acc;
    __syncthreads();
    if (wv == 0) {
#pragma unroll
      for (int s = 0; s < 3; ++s)
        acc += ((const f32x4*)red)[s * 64 + lane];
#pragma unroll
      for (int r = 0; r < 4; ++r)
        out[(mt * 16 + quad * 4 + r) * NCAT + jg] = acc[r];
    }
  }
}

extern "C" void kernel_launch(void* const* d_in, const int* in_sizes, int n_in,
                              void* d_out, int out_size, void* d_ws, size_t ws_size,
                              hipStream_t stream) {
  const float* x    = (const float*)d_in[0];
  const float* h0   = (const float*)d_in[1];
  const float* Wh   = (const float*)d_in[2];
  const float* Wz   = (const float*)d_in[3];
  const float* Uh   = (const float*)d_in[5];
  const float* Uz   = (const float*)d_in[6];
  const float* bz   = (const float*)d_in[8];
  const float* Wout = (const float*)d_in[10];

  char* ws = (char*)d_ws;
  // layout: flags [0,16K) (256 wgs x 64B, 2 cells each) | h-ring 513 x 128K
  unsigned* flags = (unsigned*)ws;
  short* ring = (short*)(ws + 16384);

  hipMemsetAsync(flags, 0, 16384, stream);

  hipFuncSetAttribute((const void*)gru_kernel,
                      hipFuncAttributeMaxDynamicSharedMemorySize, 147968);
  gru_kernel<<<256, 256, 147968, stream>>>(h0, Wh, Wz, Uh, Uz, bz, Wout, x,
                                           ring, flags, (float*)d_out);
}